// Round 5
// baseline (97.825 us; speedup 1.0000x reference)
//
#include <hip/hip_runtime.h>
#include <hip/hip_bf16.h>

// Problem constants (match reference)
#define N_OUT_ROWS 250000
#define TILES 15625      // 16-row output tiles
#define NBLK 256         // 1 block/CU (128KB LDS each)
#define WPB 4            // waves per block
#define NWAVES (NBLK * WPB)  // 1024
#define BN_EPS 1e-5f

#define SB() __builtin_amdgcn_sched_barrier(0)

typedef __attribute__((ext_vector_type(8))) short bf16x8;
typedef __attribute__((ext_vector_type(8))) unsigned short u16x8;
typedef __attribute__((ext_vector_type(4))) float f32x4;

static __device__ __forceinline__ unsigned short f2bf(float f) {
  union { float f; unsigned u; } v; v.f = f;
  unsigned r = v.u + 0x7FFFu + ((v.u >> 16) & 1u);
  return (unsigned short)(r >> 16);
}

// Fire-and-forget 16B gather into LDS (per-lane global src, linear LDS dest).
#define GLOAD_LDS16(gsrc, ldst)                                                \
  __builtin_amdgcn_global_load_lds(                                            \
      (const __attribute__((address_space(1))) unsigned int*)(gsrc),           \
      (__attribute__((address_space(3))) unsigned int*)(ldst), 16, 0, 0)

// Prep: weights f32 -> bf16 fragment layout in d_ws, zero stats.
__global__ void k_prep(const float* __restrict__ w,
                       unsigned short* __restrict__ bfrag,
                       float* __restrict__ stats) {
  const int i = blockIdx.x * 256 + threadIdx.x;  // 0..2047
  if (i < 128) stats[i] = 0.f;
  const int f = i >> 6, l = i & 63;
  const int kt = f >> 2, ct = f & 3, rr = l & 15, gg = l >> 4;
  u16x8 o;
  #pragma unroll
  for (int j = 0; j < 8; ++j)
    o[j] = f2bf(w[(kt * 32 + gg * 8 + j) * 64 + ct * 16 + rr]);
  *reinterpret_cast<u16x8*>(bfrag + i * 8) = o;
}

// Fused gather + bf16-MFMA GEMM + BN partials; cross-tile double-buffered
// gather pipeline with COUNTED vmcnt. Round-4 bug: counted waits require the
// vmem sequence to be pinned -- scheduler reordered {gathers, idx loads}
// within an asm-delimited region, shifting the true count from 36 to 34 and
// leaving 2 gathers in flight at compute start. Fix: sched_barrier(0) after
// every vmem cluster (counts now exact) + wait on the minimum legal count.
__global__ __launch_bounds__(256, 1)
void k_gemm(const float* __restrict__ x, const int* __restrict__ neigh,
            const unsigned short* __restrict__ bfrag, float* __restrict__ out,
            float* __restrict__ stats) {
  __shared__ __align__(16) unsigned char Abuf_all[WPB][2][16384];  // 128 KB

  const int tid = threadIdx.x;
  const int lane = tid & 63;
  const int widx = tid >> 6;
  unsigned char* Abuf = &Abuf_all[widx][0][0];

  // B fragments fully in registers (32 frags = 128 VGPR).
  bf16x8 bf[8][4];
  #pragma unroll
  for (int kt = 0; kt < 8; ++kt)
    #pragma unroll
    for (int ct = 0; ct < 4; ++ct)
      bf[kt][ct] = *reinterpret_cast<const bf16x8*>(
          bfrag + ((kt * 4 + ct) * 64 + lane) * 8);

  // Contiguous tile range per wave.
  const int gw = blockIdx.x * WPB + widx;  // 0..1023
  const int q = TILES / NWAVES;            // 15
  const int rem = TILES % NWAVES;          // 265
  const int start = (gw < rem) ? gw * (q + 1) : rem * (q + 1) + (gw - rem) * q;
  const int cnt = q + (gw < rem ? 1 : 0);

  const int r = lane & 15;     // A row within tile / C col-within-group
  const int g4 = lane >> 4;    // k-slice group
  const int seg = lane & 7;    // 16B segment within a 128B x-row
  const int ktl = lane >> 3;   // neighbor slot for gather addressing
  const int swz = (r & 7) << 4;
  const int rdbase = (r << 10) + (g4 << 5);

  // idx loads: 128 ints per tile, 2 coalesced dwords per lane.
  auto LDIDX = [&](int t, int& a, int& b) {
    const int tt = (t < TILES) ? t : (TILES - 1);
    const int* p = neigh + tt * 128;
    a = p[lane];
    b = p[64 + lane];
  };
  // 16 gathers for one tile; instr j stages row j's 8 neighbor rows (1KB);
  // source segment pre-permuted (seg^(j&7)) = XOR-swizzled linear LDS layout.
  auto ISSUE = [&](int bsel, int a, int b) {
    unsigned char* B = Abuf + (bsel << 14);
    #pragma unroll
    for (int j = 0; j < 16; ++j) {
      const int id = __shfl((j < 8) ? a : b, ((j & 7) << 3) + ktl, 64);
      const float* src = x + (size_t)id * 32 + ((seg ^ (j & 7)) << 2);
      GLOAD_LDS16(src, B + j * 1024);
    }
  };

  float sacc[4] = {0.f, 0.f, 0.f, 0.f};
  float qacc[4] = {0.f, 0.f, 0.f, 0.f};

  // Prologue (each vmem cluster pinned by SB so loop-wait counts are exact):
  // [bf loads + idx(t0) + idx(t1)] | G(t0) | idx(t2) |
  int cA, cB, pA, pB, nA, nB;
  LDIDX(start, cA, cB);
  LDIDX(start + 1, pA, pB);
  SB();
  ISSUE(0, cA, cB);
  SB();
  LDIDX(start + 2, nA, nB);
  SB();

  for (int k = 0; k < cnt; ++k) {
    // (a) prefetch tile k+1's gathers into the other buffer.
    if (k + 1 < cnt) {
      asm volatile("s_waitcnt lgkmcnt(0)" ::: "memory");  // WAR vs old ds_reads
      SB();
      ISSUE((k + 1) & 1, pA, pB);
      SB();
      int zA, zB;
      LDIDX(start + k + 3, zA, zB);
      SB();
      pA = nA; pB = nB; nA = zA; nB = zB;
    }

    // (b) wait for tile k's gathers (counted; in-order retirement).
    // Exact younger-than-G(t_k) counts (SB-pinned): k==0 -> 20, steady -> 36.
    // Use minimum-legal values (18/34): waits 2 extra idx loads, ~free.
    if (k == cnt - 1)      asm volatile("s_waitcnt vmcnt(0)" ::: "memory");
    else if (k == 0)       asm volatile("s_waitcnt vmcnt(18)" ::: "memory");
    else                   asm volatile("s_waitcnt vmcnt(34)" ::: "memory");
    SB();

    const unsigned char* B = Abuf + ((k & 1) << 14);
    f32x4 acc[4];
    #pragma unroll
    for (int ct = 0; ct < 4; ++ct) acc[ct] = (f32x4){0.f, 0.f, 0.f, 0.f};

    #pragma unroll
    for (int kt = 0; kt < 8; ++kt) {
      const int o0 = rdbase + (kt << 7);
      const f32x4 a0 = *reinterpret_cast<const f32x4*>(B + (o0 ^ swz));
      const f32x4 a1 = *reinterpret_cast<const f32x4*>(B + ((o0 + 16) ^ swz));
      union { bf16x8 v; __hip_bfloat162 h[4]; } af;
      af.h[0] = __float22bfloat162_rn(make_float2(a0[0], a0[1]));
      af.h[1] = __float22bfloat162_rn(make_float2(a0[2], a0[3]));
      af.h[2] = __float22bfloat162_rn(make_float2(a1[0], a1[1]));
      af.h[3] = __float22bfloat162_rn(make_float2(a1[2], a1[3]));
      #pragma unroll
      for (int ct = 0; ct < 4; ++ct)
        acc[ct] = __builtin_amdgcn_mfma_f32_16x16x32_bf16(af.v, bf[kt][ct],
                                                          acc[ct], 0, 0, 0);
    }

    // C write: col = ct*16 + r, row = g4*4 + j; accumulate BN partials.
    const int rbase = ((start + k) << 4) + g4 * 4;
    #pragma unroll
    for (int ct = 0; ct < 4; ++ct) {
      #pragma unroll
      for (int j = 0; j < 4; ++j)
        out[(rbase + j) * 64 + ct * 16 + r] = acc[ct][j];
      sacc[ct] += acc[ct][0] + acc[ct][1] + acc[ct][2] + acc[ct][3];
      qacc[ct] += acc[ct][0] * acc[ct][0] + acc[ct][1] * acc[ct][1] +
                  acc[ct][2] * acc[ct][2] + acc[ct][3] * acc[ct][3];
    }
  }

  // Per-wave BN reduction (no LDS, no barrier): fold g4 groups, then 8 atomic
  // instructions per wave onto the 128 stats slots.
  #pragma unroll
  for (int ct = 0; ct < 4; ++ct) {
    sacc[ct] += __shfl_xor(sacc[ct], 16);
    qacc[ct] += __shfl_xor(qacc[ct], 16);
    sacc[ct] += __shfl_xor(sacc[ct], 32);
    qacc[ct] += __shfl_xor(qacc[ct], 32);
  }
  if (lane < 16) {
    #pragma unroll
    for (int ct = 0; ct < 4; ++ct) {
      atomicAdd(&stats[ct * 16 + lane], sacc[ct]);
      atomicAdd(&stats[64 + ct * 16 + lane], qacc[ct]);
    }
  }
}

// Finalize BN: y = (out - mean) * rsqrt(var+eps) * gamma + beta, in place.
__global__ __launch_bounds__(256)
void k_bn(float* __restrict__ out, const float* __restrict__ stats,
          const float* __restrict__ gamma, const float* __restrict__ beta) {
  __shared__ float sc[64], bs[64];
  if (threadIdx.x < 64) {
    const int d = threadIdx.x;
    const float inv = 1.0f / (float)N_OUT_ROWS;
    const float mean = stats[d] * inv;
    const float var = stats[64 + d] * inv - mean * mean;
    const float rstd = rsqrtf(var + BN_EPS);
    const float scale = rstd * gamma[d];
    sc[d] = scale;
    bs[d] = beta[d] - mean * scale;
  }
  __syncthreads();

  const int total4 = N_OUT_ROWS * 64 / 4;  // 4,000,000 float4s
  float4* o4 = reinterpret_cast<float4*>(out);
  for (int i = blockIdx.x * blockDim.x + threadIdx.x; i < total4;
       i += gridDim.x * blockDim.x) {
    const int d0 = (i & 15) << 2;
    float4 v = o4[i];
    v.x = v.x * sc[d0]     + bs[d0];
    v.y = v.y * sc[d0 + 1] + bs[d0 + 1];
    v.z = v.z * sc[d0 + 2] + bs[d0 + 2];
    v.w = v.w * sc[d0 + 3] + bs[d0 + 3];
    o4[i] = v;
  }
}

extern "C" void kernel_launch(void* const* d_in, const int* in_sizes, int n_in,
                              void* d_out, int out_size, void* d_ws, size_t ws_size,
                              hipStream_t stream) {
  const float* x     = (const float*)d_in[0];
  const int*   neigh = (const int*)d_in[1];
  const float* w     = (const float*)d_in[2];
  const float* gamma = (const float*)d_in[3];
  const float* beta  = (const float*)d_in[4];
  float* out = (float*)d_out;

  float* stats = (float*)d_ws;                                   // 128 f32
  unsigned short* bfrag = (unsigned short*)((char*)d_ws + 1024); // 32 KB

  k_prep<<<8, 256, 0, stream>>>(w, bfrag, stats);
  k_gemm<<<NBLK, 256, 0, stream>>>(x, neigh, bfrag, out, stats);
  k_bn<<<2048, 256, 0, stream>>>(out, stats, gamma, beta);
}